// Round 3
// baseline (329.490 us; speedup 1.0000x reference)
//
#include <hip/hip_runtime.h>
#include <hip/hip_bf16.h>
#include <cstdint>

typedef _Float16 half8 __attribute__((ext_vector_type(8)));
typedef float f32x4 __attribute__((ext_vector_type(4)));

#define B_DIM 8
#define C_DIM 512
#define H_DIM 512
#define T_DIM 4096
#define KTOT 1024   // 2*C
#define MTOT 2048   // 4*H, interleaved m = 4*h + gate (z,f,o,i)

__device__ __forceinline__ void gload16(const void* g, void* l) {
  __builtin_amdgcn_global_load_lds(
      (const __attribute__((address_space(1))) unsigned int*)g,
      (__attribute__((address_space(3))) unsigned int*)l, 16, 0, 0);
}

__device__ __forceinline__ float sigmoidf_(float x) { return 1.0f / (1.0f + expf(-x)); }

// ---------------------------------------------------------------------------
// K0: pack weights fp32 [H][C][2] (4 gates) -> fp16 A16[m=4h+g][k=j*512+c]
// ---------------------------------------------------------------------------
__global__ __launch_bounds__(256) void pack_w(
    const float* __restrict__ wz, const float* __restrict__ wf,
    const float* __restrict__ wo, const float* __restrict__ wi,
    _Float16* __restrict__ A16) {
  int idx = blockIdx.x * 256 + threadIdx.x;        // [0, 2048*1024)
  int m = idx >> 10, k = idx & 1023;
  int h = m >> 2, g = m & 3;
  int j = k >> 9, c = k & 511;
  const float* w = (g == 0) ? wz : (g == 1) ? wf : (g == 2) ? wo : wi;
  A16[idx] = (_Float16)w[(h << 10) + (c << 1) + j];
}

// ---------------------------------------------------------------------------
// K1: transpose+convert x fp32 [B][C][T] -> XTg fp16 [B][T+1][512]
//     row 0 of each b is a zeroed guard (t = -1); XT1[b][t][c] = x[b][c][t].
// ---------------------------------------------------------------------------
__global__ __launch_bounds__(256) void transpose_x(
    const float* __restrict__ x, _Float16* __restrict__ XTg) {
  int bid = blockIdx.x;            // B * 8 * 64
  int b = bid >> 9;
  int rem = bid & 511;
  int c0 = (rem >> 6) * 64;
  int t0 = (rem & 63) * 64;
  __shared__ _Float16 tile[64][73];
  int tid = threadIdx.x;
#pragma unroll
  for (int it = 0; it < 4; ++it) {
    int idx = it * 256 + tid;      // 1024 tasks: 64 rows x 16 float4
    int ci = idx >> 4, tc = idx & 15;
    float4 v = *(const float4*)(x + (((size_t)b * C_DIM + c0 + ci) * T_DIM + t0 + tc * 4));
    tile[ci][tc * 4 + 0] = (_Float16)v.x;
    tile[ci][tc * 4 + 1] = (_Float16)v.y;
    tile[ci][tc * 4 + 2] = (_Float16)v.z;
    tile[ci][tc * 4 + 3] = (_Float16)v.w;
  }
  __syncthreads();
#pragma unroll
  for (int it = 0; it < 2; ++it) {
    int idx = it * 256 + tid;      // 512 tasks: 64 t-rows x 8 c-blocks
    int tr = idx >> 3, cb = idx & 7;
    half8 h;
#pragma unroll
    for (int e = 0; e < 8; ++e) h[e] = tile[cb * 8 + e][tr];
    int t = t0 + tr;
    *(half8*)(XTg + ((size_t)b * (T_DIM + 1) + 1 + t) * 512 + c0 + cb * 8) = h;
  }
  if (t0 == 0 && tid < 8) {        // zero guard row (t = -1)
    half8 z = {};
    *(half8*)(XTg + ((size_t)b * (T_DIM + 1)) * 512 + c0 + tid * 8) = z;
  }
}

// ---------------------------------------------------------------------------
// K2: 256x256 8-phase GEMM, BK=64, 8 waves (2M x 4N), mfma_f32_16x16x32_f16.
//  LDS (128KB dynamic): buf[u&1] (64KB) = [Aq0 16K][Aq1 16K][Bs0 16K][Bs1 16K]
//  Region row maps (wave-interleaved so each phase reads exactly one region):
//   A region q, row r(0..127): m = m0 + (r>>6)*128 + q*64 + (r&63)
//   B region s, row r(0..127): t = t0 + (r>>5)*64 + s*32 + (r&31)
//  16B-block XOR swizzle: LDS linear, global src blk = blk ^ (row&7).
//  Phases per tile u (quad = 16 MFMA):
//   P1: ds A q0(8)+B s0(4); stage Bs1(u+1);  quad acc[0..3][0..1]
//   P2: ds B s1(4);         stage Aq0(u+2);  quad acc[0..3][2..3]
//   P3: ds A q1(8);         stage Bs0(u+2);  quad acc[4..7][0..1]  (bb s0 live)
//   P4: -;                  stage Aq1(u+2); vmcnt(6|0); quad acc[4..7][2..3]
//  WAR ledger: each region's stage is issued >=1 phase after its reads complete
//  (reads retired by that phase's lgkmcnt(0) + trailing barrier).
//  RAW: vmcnt(6) at P4(u) retires everything except the 3 newest half-tiles
//  (Aq0,Bs0,Aq1 of tile u+2) => tile u+1 fully in LDS before P1(u+1).
// ---------------------------------------------------------------------------
__global__ __launch_bounds__(512, 2) void qrnn_gemm2(
    const _Float16* __restrict__ A16, const _Float16* __restrict__ XTg,
    const float* __restrict__ bz, const float* __restrict__ bf,
    const float* __restrict__ bo, const float* __restrict__ bi,
    _Float16* __restrict__ F, _Float16* __restrict__ G, _Float16* __restrict__ O) {
  extern __shared__ char lds[];
  int bid = blockIdx.x;                       // 1024 = 8b * 8m * 16t
  int swz = (bid & 7) * 128 + (bid >> 3);     // XCD-contiguous (1024%8==0)
  int b = swz >> 7;                           // one b per XCD
  int rem = swz & 127;
  int t0 = (rem >> 3) * 256;                  // t-major within XCD
  int m0 = (rem & 7) * 256;
  int tid = threadIdx.x;
  int lane = tid & 63, wid = tid >> 6;
  int wr = wid >> 2, wc = wid & 3;
  int lg = lane >> 4, l7 = lane & 7, l15 = lane & 15;

  int blkoff0 = (lg ^ l7) << 4;
  int blkoff1 = ((4 + lg) ^ l7) << 4;
  int aoffA[4], boffB[4];
#pragma unroll
  for (int ii = 0; ii < 4; ++ii) aoffA[ii] = (wr * 64 + ii * 16 + l15) * 128;
#pragma unroll
  for (int nf = 0; nf < 4; ++nf)
    boffB[nf] = 32768 + (nf >> 1) * 16384 + (wc * 32 + (nf & 1) * 16 + l15) * 128;

  int srow = tid >> 3;                        // 0..63
  int gblk = (tid & 7) ^ (srow & 7);
  int aStageOff = (m0 + srow) * 1024 + gblk * 8;
  size_t bStageOff =
      ((size_t)b * (T_DIM + 1) + 1 + t0 + (srow >> 5) * 64 + (srow & 31)) * 512 + gblk * 8;

  auto stageA = [&](int q, int u2) {
    char* dst = lds + ((u2 & 1) << 16) + q * 16384 + tid * 16;
    const _Float16* g = A16 + aStageOff + q * 65536 + u2 * 64;
    gload16(g, dst);
    gload16(g + 131072, dst + 8192);          // rows +128
  };
  auto stageB = [&](int s, int u2) {
    char* dst = lds + ((u2 & 1) << 16) + 32768 + s * 16384 + tid * 16;
    const _Float16* g = XTg + bStageOff + s * 16384 + ((u2 & 7) << 6)
                        - ((u2 < 8) ? 512 : 0);   // tap0 = row t-1 (guard at t=-1)
    gload16(g, dst);
    gload16(g + 65536, dst + 8192);           // t-rows +128
  };

  f32x4 acc[8][4];
#pragma unroll
  for (int i = 0; i < 8; ++i)
#pragma unroll
    for (int j = 0; j < 4; ++j) acc[i][j] = (f32x4){0.f, 0.f, 0.f, 0.f};
  half8 a[4][2], bb[4][2];

  // prologue: fully stage tiles 0 and 1 (16 loads); retire tile 0.
  stageA(0, 0); stageB(0, 0); stageB(1, 0); stageA(1, 0);
  stageA(0, 1); stageB(0, 1); stageB(1, 1); stageA(1, 1);
  asm volatile("s_waitcnt vmcnt(8)" ::: "memory");
  __builtin_amdgcn_sched_barrier(0);
  __builtin_amdgcn_s_barrier();
  __builtin_amdgcn_sched_barrier(0);

#define PHASE_TAIL()                                         \
  __builtin_amdgcn_sched_barrier(0);                         \
  __builtin_amdgcn_s_barrier();                              \
  asm volatile("s_waitcnt lgkmcnt(0)" ::: "memory");         \
  __builtin_amdgcn_sched_barrier(0);                         \
  __builtin_amdgcn_s_setprio(1);

#define PHASE_END()                                          \
  __builtin_amdgcn_s_setprio(0);                             \
  __builtin_amdgcn_sched_barrier(0);                         \
  __builtin_amdgcn_s_barrier();                              \
  __builtin_amdgcn_sched_barrier(0);

  for (int u = 0; u < 16; ++u) {
    int dbuf = (u & 1) << 16;
    // ---- P1: read A q0 + B s0; stage Bs1(u+1); quad (mi=0, n=0..1)
#pragma unroll
    for (int ii = 0; ii < 4; ++ii) {
      a[ii][0] = *(const half8*)(lds + dbuf + aoffA[ii] + blkoff0);
      a[ii][1] = *(const half8*)(lds + dbuf + aoffA[ii] + blkoff1);
    }
#pragma unroll
    for (int nf = 0; nf < 2; ++nf) {
      bb[nf][0] = *(const half8*)(lds + dbuf + boffB[nf] + blkoff0);
      bb[nf][1] = *(const half8*)(lds + dbuf + boffB[nf] + blkoff1);
    }
    if (u >= 1 && u <= 14) stageB(1, u + 1);
    PHASE_TAIL()
#pragma unroll
    for (int ii = 0; ii < 4; ++ii)
#pragma unroll
      for (int nf = 0; nf < 2; ++nf) {
        acc[ii][nf] = __builtin_amdgcn_mfma_f32_16x16x32_f16(a[ii][0], bb[nf][0], acc[ii][nf], 0, 0, 0);
        acc[ii][nf] = __builtin_amdgcn_mfma_f32_16x16x32_f16(a[ii][1], bb[nf][1], acc[ii][nf], 0, 0, 0);
      }
    PHASE_END()

    // ---- P2: read B s1; stage Aq0(u+2); quad (mi=0, n=2..3)
#pragma unroll
    for (int nf = 2; nf < 4; ++nf) {
      bb[nf][0] = *(const half8*)(lds + dbuf + boffB[nf] + blkoff0);
      bb[nf][1] = *(const half8*)(lds + dbuf + boffB[nf] + blkoff1);
    }
    if (u <= 13) stageA(0, u + 2);
    PHASE_TAIL()
#pragma unroll
    for (int ii = 0; ii < 4; ++ii)
#pragma unroll
      for (int nf = 2; nf < 4; ++nf) {
        acc[ii][nf] = __builtin_amdgcn_mfma_f32_16x16x32_f16(a[ii][0], bb[nf][0], acc[ii][nf], 0, 0, 0);
        acc[ii][nf] = __builtin_amdgcn_mfma_f32_16x16x32_f16(a[ii][1], bb[nf][1], acc[ii][nf], 0, 0, 0);
      }
    PHASE_END()

    // ---- P3: read A q1; stage Bs0(u+2); quad (mi=1, n=0..1), bb[0..1] live
#pragma unroll
    for (int ii = 0; ii < 4; ++ii) {
      a[ii][0] = *(const half8*)(lds + dbuf + 16384 + aoffA[ii] + blkoff0);
      a[ii][1] = *(const half8*)(lds + dbuf + 16384 + aoffA[ii] + blkoff1);
    }
    if (u <= 13) stageB(0, u + 2);
    PHASE_TAIL()
#pragma unroll
    for (int ii = 0; ii < 4; ++ii)
#pragma unroll
      for (int nf = 0; nf < 2; ++nf) {
        acc[4 + ii][nf] = __builtin_amdgcn_mfma_f32_16x16x32_f16(a[ii][0], bb[nf][0], acc[4 + ii][nf], 0, 0, 0);
        acc[4 + ii][nf] = __builtin_amdgcn_mfma_f32_16x16x32_f16(a[ii][1], bb[nf][1], acc[4 + ii][nf], 0, 0, 0);
      }
    PHASE_END()

    // ---- P4: no reads; stage Aq1(u+2); counted vmcnt; quad (mi=1, n=2..3)
    if (u <= 13) stageA(1, u + 2);
    if (u < 14) {
      asm volatile("s_waitcnt vmcnt(6)" ::: "memory");
    } else if (u == 14) {
      asm volatile("s_waitcnt vmcnt(0)" ::: "memory");
    }
    PHASE_TAIL()
#pragma unroll
    for (int ii = 0; ii < 4; ++ii)
#pragma unroll
      for (int nf = 2; nf < 4; ++nf) {
        acc[4 + ii][nf] = __builtin_amdgcn_mfma_f32_16x16x32_f16(a[ii][0], bb[nf][0], acc[4 + ii][nf], 0, 0, 0);
        acc[4 + ii][nf] = __builtin_amdgcn_mfma_f32_16x16x32_f16(a[ii][1], bb[nf][1], acc[4 + ii][nf], 0, 0, 0);
      }
    PHASE_END()
  }
#undef PHASE_TAIL
#undef PHASE_END

  // epilogue: m = 4h+gate; lane-group lg holds gates 0..3 of h = (mbase>>2)+lg
#pragma unroll
  for (int i = 0; i < 8; ++i) {
    int h = ((m0 + wr * 128 + i * 16) >> 2) + lg;
    float vbz = bz[h], vbf = bf[h], vbo = bo[h], vbi = bi[h];
#pragma unroll
    for (int j = 0; j < 4; ++j) {
      int t = t0 + wc * 64 + j * 16 + l15;
      float yz = acc[i][j][0] + vbz;
      float yf = acc[i][j][1] + vbf;
      float yo = acc[i][j][2] + vbo;
      float yi = acc[i][j][3] + vbi;
      float zz = tanhf(yz);
      float ff = sigmoidf_(yf);
      float oo = sigmoidf_(yo);
      float ii2 = sigmoidf_(yi);
      size_t gi = ((size_t)b * H_DIM + h) * T_DIM + t;
      F[gi] = (_Float16)ff;
      G[gi] = (_Float16)(ii2 * zz);
      O[gi] = (_Float16)oo;
    }
  }
}

// ---------------------------------------------------------------------------
// K3: fused scan. One block per (b,h) row (4096 blocks x 256 threads).
// ---------------------------------------------------------------------------
__global__ __launch_bounds__(256) void scan_fused(
    const _Float16* __restrict__ F, const _Float16* __restrict__ G,
    const _Float16* __restrict__ O, float* __restrict__ out) {
  __shared__ char smem[24 * 1024 + 64];
  _Float16* sF = (_Float16*)smem;              // 8KB: 512 16B-blocks
  _Float16* sG = (_Float16*)(smem + 8192);
  _Float16* sO = (_Float16*)(smem + 16384);
  float* sOut = (float*)smem;                  // 16KB, aliases sF+sG
  float* wFs = (float*)(smem + 24576);
  float* wGs = wFs + 4;

  int tid = threadIdx.x;
  int lane = tid & 63, wv = tid >> 6;
  size_t base = (size_t)blockIdx.x * T_DIM;
  const _Float16* Fg = F + base;
  const _Float16* Gg = G + base;
  const _Float16* Og = O + base;

#pragma unroll
  for (int it = 0; it < 2; ++it) {
    int idx = it * 256 + tid;
    int sb = idx ^ ((idx >> 3) & 7);
    gload16(Fg + sb * 8, (char*)sF + idx * 16);
    gload16(Gg + sb * 8, (char*)sG + idx * 16);
    gload16(Og + sb * 8, (char*)sO + idx * 16);
  }
  asm volatile("s_waitcnt vmcnt(0)" ::: "memory");
  __syncthreads();

  int i = tid;
  int b0 = (2 * i) ^ (((2 * i) >> 3) & 7);
  int b1 = (2 * i + 1) ^ (((2 * i + 1) >> 3) & 7);
  half8 f0 = *(half8*)((char*)sF + b0 * 16);
  half8 f1 = *(half8*)((char*)sF + b1 * 16);
  half8 g0 = *(half8*)((char*)sG + b0 * 16);
  half8 g1 = *(half8*)((char*)sG + b1 * 16);
  half8 o0 = *(half8*)((char*)sO + b0 * 16);
  half8 o1 = *(half8*)((char*)sO + b1 * 16);

  float Fp = 1.f, Gc = 0.f;
#pragma unroll
  for (int e = 0; e < 8; ++e) {
    float fe = (float)f0[e];
    Gc = fe * Gc + (float)g0[e];
    Fp *= fe;
  }
#pragma unroll
  for (int e = 0; e < 8; ++e) {
    float fe = (float)f1[e];
    Gc = fe * Gc + (float)g1[e];
    Fp *= fe;
  }

  float Fs = Fp, Gs = Gc;
#pragma unroll
  for (int d = 1; d < 64; d <<= 1) {
    float Fo = __shfl_up(Fs, d);
    float Go = __shfl_up(Gs, d);
    if (lane >= d) { Gs = Fs * Go + Gs; Fs = Fs * Fo; }
  }
  if (lane == 63) { wFs[wv] = Fs; wGs[wv] = Gs; }
  __syncthreads();
  float carry = 0.f;
  for (int w = 0; w < wv; ++w) carry = wFs[w] * carry + wGs[w];
  float Fpr = __shfl_up(Fs, 1);
  float Gpr = __shfl_up(Gs, 1);
  float cin = (lane == 0) ? carry : Fpr * carry + Gpr;

  float c = cin;
  float4 r0, r1, r2, r3;
#define QSTEP(fv, gv, ov, e, dst) \
  { c = (float)fv[e] * c + (float)gv[e]; dst = (float)ov[e] * c; }
  QSTEP(f0, g0, o0, 0, r0.x) QSTEP(f0, g0, o0, 1, r0.y)
  QSTEP(f0, g0, o0, 2, r0.z) QSTEP(f0, g0, o0, 3, r0.w)
  QSTEP(f0, g0, o0, 4, r1.x) QSTEP(f0, g0, o0, 5, r1.y)
  QSTEP(f0, g0, o0, 6, r1.z) QSTEP(f0, g0, o0, 7, r1.w)
  QSTEP(f1, g1, o1, 0, r2.x) QSTEP(f1, g1, o1, 1, r2.y)
  QSTEP(f1, g1, o1, 2, r2.z) QSTEP(f1, g1, o1, 3, r2.w)
  QSTEP(f1, g1, o1, 4, r3.x) QSTEP(f1, g1, o1, 5, r3.y)
  QSTEP(f1, g1, o1, 6, r3.z) QSTEP(f1, g1, o1, 7, r3.w)
#undef QSTEP
  {
    int obl = 4 * i;
    int s0 = (obl + 0) ^ (((obl + 0) >> 3) & 7);
    int s1 = (obl + 1) ^ (((obl + 1) >> 3) & 7);
    int s2 = (obl + 2) ^ (((obl + 2) >> 3) & 7);
    int s3 = (obl + 3) ^ (((obl + 3) >> 3) & 7);
    *(float4*)((char*)sOut + s0 * 16) = r0;
    *(float4*)((char*)sOut + s1 * 16) = r1;
    *(float4*)((char*)sOut + s2 * 16) = r2;
    *(float4*)((char*)sOut + s3 * 16) = r3;
  }
  __syncthreads();

  float* og = out + base;
#pragma unroll
  for (int it = 0; it < 4; ++it) {
    int idx = it * 256 + tid;
    int sb = idx ^ ((idx >> 3) & 7);
    *(float4*)(og + idx * 4) = *(float4*)((char*)sOut + sb * 16);
  }
}

// ---------------------------------------------------------------------------
extern "C" void kernel_launch(void* const* d_in, const int* in_sizes, int n_in,
                              void* d_out, int out_size, void* d_ws, size_t ws_size,
                              hipStream_t stream) {
  (void)in_sizes; (void)n_in; (void)out_size; (void)ws_size;
  const float* x  = (const float*)d_in[0];
  const float* wz = (const float*)d_in[1];
  const float* bz = (const float*)d_in[2];
  const float* wf = (const float*)d_in[3];
  const float* bf = (const float*)d_in[4];
  const float* wo = (const float*)d_in[5];
  const float* bo = (const float*)d_in[6];
  const float* wi = (const float*)d_in[7];
  const float* bi = (const float*)d_in[8];

  char* ws = (char*)d_ws;
  const size_t MB = 1ull << 20;
  _Float16* A16 = (_Float16*)(ws);                 //   4 MB
  _Float16* XTg = (_Float16*)(ws + 4 * MB);        //  ~32.01 MB  [B][T+1][512]
  _Float16* F   = (_Float16*)(ws + 40 * MB);       //  32 MB
  _Float16* G   = (_Float16*)(ws + 72 * MB);       //  32 MB
  _Float16* O   = (_Float16*)(ws + 104 * MB);      //  32 MB

  hipFuncSetAttribute((const void*)qrnn_gemm2,
                      hipFuncAttributeMaxDynamicSharedMemorySize, 131072);

  pack_w<<<(MTOT * KTOT) / 256, 256, 0, stream>>>(wz, wf, wo, wi, A16);
  transpose_x<<<B_DIM * 8 * 64, 256, 0, stream>>>(x, XTg);
  qrnn_gemm2<<<B_DIM * 8 * 16, 512, 131072, stream>>>(A16, XTg, bz, bf, bo, bi, F, G, O);
  scan_fused<<<B_DIM * H_DIM, 256, 0, stream>>>(F, G, O, (float*)d_out);
}

// Round 4
// 328.866 us; speedup vs baseline: 1.0019x; 1.0019x over previous
//
#include <hip/hip_runtime.h>
#include <hip/hip_bf16.h>
#include <cstdint>

typedef _Float16 half8 __attribute__((ext_vector_type(8)));
typedef float f32x4 __attribute__((ext_vector_type(4)));

#define B_DIM 8
#define C_DIM 512
#define H_DIM 512
#define T_DIM 4096
#define KTOT 1024   // 2*C
#define MTOT 2048   // 4*H, interleaved m = 4*h + gate (z,f,o,i)

__device__ __forceinline__ void gload16(const void* g, void* l) {
  __builtin_amdgcn_global_load_lds(
      (const __attribute__((address_space(1))) unsigned int*)g,
      (__attribute__((address_space(3))) unsigned int*)l, 16, 0, 0);
}

__device__ __forceinline__ float sigmoidf_(float x) { return 1.0f / (1.0f + expf(-x)); }

// ---------------------------------------------------------------------------
// K0: pack weights fp32 [H][C][2] (4 gates) -> fp16 A16[m=4h+g][k=j*512+c]
// ---------------------------------------------------------------------------
__global__ __launch_bounds__(256) void pack_w(
    const float* __restrict__ wz, const float* __restrict__ wf,
    const float* __restrict__ wo, const float* __restrict__ wi,
    _Float16* __restrict__ A16) {
  int idx = blockIdx.x * 256 + threadIdx.x;        // [0, 2048*1024)
  int m = idx >> 10, k = idx & 1023;
  int h = m >> 2, g = m & 3;
  int j = k >> 9, c = k & 511;
  const float* w = (g == 0) ? wz : (g == 1) ? wf : (g == 2) ? wo : wi;
  A16[idx] = (_Float16)w[(h << 10) + (c << 1) + j];
}

// ---------------------------------------------------------------------------
// K1: transpose+convert x fp32 [B][C][T] -> XTg fp16 [B][T+1][512]
//     row 0 of each b is a zeroed guard (t = -1); XT1[b][t][c] = x[b][c][t].
// ---------------------------------------------------------------------------
__global__ __launch_bounds__(256) void transpose_x(
    const float* __restrict__ x, _Float16* __restrict__ XTg) {
  int bid = blockIdx.x;            // B * 8 * 64
  int b = bid >> 9;
  int rem = bid & 511;
  int c0 = (rem >> 6) * 64;
  int t0 = (rem & 63) * 64;
  __shared__ _Float16 tile[64][73];
  int tid = threadIdx.x;
#pragma unroll
  for (int it = 0; it < 4; ++it) {
    int idx = it * 256 + tid;      // 1024 tasks: 64 rows x 16 float4
    int ci = idx >> 4, tc = idx & 15;
    float4 v = *(const float4*)(x + (((size_t)b * C_DIM + c0 + ci) * T_DIM + t0 + tc * 4));
    tile[ci][tc * 4 + 0] = (_Float16)v.x;
    tile[ci][tc * 4 + 1] = (_Float16)v.y;
    tile[ci][tc * 4 + 2] = (_Float16)v.z;
    tile[ci][tc * 4 + 3] = (_Float16)v.w;
  }
  __syncthreads();
#pragma unroll
  for (int it = 0; it < 2; ++it) {
    int idx = it * 256 + tid;      // 512 tasks: 64 t-rows x 8 c-blocks
    int tr = idx >> 3, cb = idx & 7;
    half8 h;
#pragma unroll
    for (int e = 0; e < 8; ++e) h[e] = tile[cb * 8 + e][tr];
    int t = t0 + tr;
    *(half8*)(XTg + ((size_t)b * (T_DIM + 1) + 1 + t) * 512 + c0 + cb * 8) = h;
  }
  if (t0 == 0 && tid < 8) {        // zero guard row (t = -1)
    half8 z = {};
    *(half8*)(XTg + ((size_t)b * (T_DIM + 1)) * 512 + c0 + tid * 8) = z;
  }
}

// ---------------------------------------------------------------------------
// K2: 256x256 8-phase GEMM, BK=64, 8 waves (2M x 4N), mfma_f32_16x16x32_f16.
//  LDS (128KB dynamic): buf[u&1] (64KB) = [Aq0 16K][Aq1 16K][Bs0 16K][Bs1 16K]
//  Region row maps (wave-interleaved so each phase reads exactly one region):
//   A region q, row r(0..127): m = m0 + (r>>6)*128 + q*64 + (r&63)
//   B region s, row r(0..127): t = t0 + (r>>5)*64 + s*32 + (r&31)
//  16B-block XOR swizzle: LDS linear, global src blk = blk ^ (row&7).
//  Phases per tile u (quad = 16 MFMA):
//   P1: ds A q0(8)+B s0(4); stage Bs1(u+1);  quad acc[0..3][0..1]
//   P2: ds B s1(4);         stage Aq0(u+2);  quad acc[0..3][2..3]
//   P3: ds A q1(8);         stage Bs0(u+2);  quad acc[4..7][0..1]  (bb s0 live)
//   P4: -;                  stage Aq1(u+2); vmcnt(6|0); quad acc[4..7][2..3]
//  WAR ledger: each region's stage is issued >=3 barriers after its reads
//  retire (per-wave lgkmcnt(0) precedes that phase's MFMA; trailing barrier
//  then syncs all waves) -> safe without sched_barrier pinning.
//  RAW: vmcnt(6) at P4(u) retires everything except the 3 newest half-tiles
//  (Aq0,Bs0,Aq1 of tile u+2) => tile u+1 fully in LDS before P1(u+1).
//  NOTE r4: removed all sched_barrier(0) walls (m141 order-pinning regression:
//  they serialized addr-VALU/ds_read issue against MFMA; compiler's own
//  lgkmcnt tracking orders ds_read->MFMA, asm "memory" orders the waitcnts).
// ---------------------------------------------------------------------------
__global__ __launch_bounds__(512, 2) void qrnn_gemm2(
    const _Float16* __restrict__ A16, const _Float16* __restrict__ XTg,
    const float* __restrict__ bz, const float* __restrict__ bf,
    const float* __restrict__ bo, const float* __restrict__ bi,
    _Float16* __restrict__ F, _Float16* __restrict__ G, _Float16* __restrict__ O) {
  extern __shared__ char lds[];
  int bid = blockIdx.x;                       // 1024 = 8b * 8m * 16t
  int swz = (bid & 7) * 128 + (bid >> 3);     // XCD-contiguous (1024%8==0)
  int b = swz >> 7;                           // one b per XCD
  int rem = swz & 127;
  int t0 = (rem >> 3) * 256;                  // t-major within XCD
  int m0 = (rem & 7) * 256;
  int tid = threadIdx.x;
  int lane = tid & 63, wid = tid >> 6;
  int wr = wid >> 2, wc = wid & 3;
  int lg = lane >> 4, l7 = lane & 7, l15 = lane & 15;

  int blkoff0 = (lg ^ l7) << 4;
  int blkoff1 = ((4 + lg) ^ l7) << 4;
  int aoffA[4], boffB[4];
#pragma unroll
  for (int ii = 0; ii < 4; ++ii) aoffA[ii] = (wr * 64 + ii * 16 + l15) * 128;
#pragma unroll
  for (int nf = 0; nf < 4; ++nf)
    boffB[nf] = 32768 + (nf >> 1) * 16384 + (wc * 32 + (nf & 1) * 16 + l15) * 128;

  int srow = tid >> 3;                        // 0..63
  int gblk = (tid & 7) ^ (srow & 7);
  int aStageOff = (m0 + srow) * 1024 + gblk * 8;
  size_t bStageOff =
      ((size_t)b * (T_DIM + 1) + 1 + t0 + (srow >> 5) * 64 + (srow & 31)) * 512 + gblk * 8;

  auto stageA = [&](int q, int u2) {
    char* dst = lds + ((u2 & 1) << 16) + q * 16384 + tid * 16;
    const _Float16* g = A16 + aStageOff + q * 65536 + u2 * 64;
    gload16(g, dst);
    gload16(g + 131072, dst + 8192);          // rows +128
  };
  auto stageB = [&](int s, int u2) {
    char* dst = lds + ((u2 & 1) << 16) + 32768 + s * 16384 + tid * 16;
    const _Float16* g = XTg + bStageOff + s * 16384 + ((u2 & 7) << 6)
                        - ((u2 < 8) ? 512 : 0);   // tap0 = row t-1 (guard at t=-1)
    gload16(g, dst);
    gload16(g + 65536, dst + 8192);           // t-rows +128
  };

  f32x4 acc[8][4];
#pragma unroll
  for (int i = 0; i < 8; ++i)
#pragma unroll
    for (int j = 0; j < 4; ++j) acc[i][j] = (f32x4){0.f, 0.f, 0.f, 0.f};
  half8 a[4][2], bb[4][2];

  // prologue: fully stage tiles 0 and 1 (16 loads); retire tile 0.
  stageA(0, 0); stageB(0, 0); stageB(1, 0); stageA(1, 0);
  stageA(0, 1); stageB(0, 1); stageB(1, 1); stageA(1, 1);
  asm volatile("s_waitcnt vmcnt(8)" ::: "memory");
  __builtin_amdgcn_s_barrier();

#define PHASE_TAIL()                                         \
  __builtin_amdgcn_s_barrier();                              \
  asm volatile("s_waitcnt lgkmcnt(0)" ::: "memory");         \
  __builtin_amdgcn_s_setprio(1);

#define PHASE_END()                                          \
  __builtin_amdgcn_s_setprio(0);                             \
  __builtin_amdgcn_s_barrier();

  for (int u = 0; u < 16; ++u) {
    int dbuf = (u & 1) << 16;
    // ---- P1: read A q0 + B s0; stage Bs1(u+1); quad (mi=0, n=0..1)
#pragma unroll
    for (int ii = 0; ii < 4; ++ii) {
      a[ii][0] = *(const half8*)(lds + dbuf + aoffA[ii] + blkoff0);
      a[ii][1] = *(const half8*)(lds + dbuf + aoffA[ii] + blkoff1);
    }
#pragma unroll
    for (int nf = 0; nf < 2; ++nf) {
      bb[nf][0] = *(const half8*)(lds + dbuf + boffB[nf] + blkoff0);
      bb[nf][1] = *(const half8*)(lds + dbuf + boffB[nf] + blkoff1);
    }
    if (u >= 1 && u <= 14) stageB(1, u + 1);
    PHASE_TAIL()
#pragma unroll
    for (int ii = 0; ii < 4; ++ii)
#pragma unroll
      for (int nf = 0; nf < 2; ++nf) {
        acc[ii][nf] = __builtin_amdgcn_mfma_f32_16x16x32_f16(a[ii][0], bb[nf][0], acc[ii][nf], 0, 0, 0);
        acc[ii][nf] = __builtin_amdgcn_mfma_f32_16x16x32_f16(a[ii][1], bb[nf][1], acc[ii][nf], 0, 0, 0);
      }
    PHASE_END()

    // ---- P2: read B s1; stage Aq0(u+2); quad (mi=0, n=2..3)
#pragma unroll
    for (int nf = 2; nf < 4; ++nf) {
      bb[nf][0] = *(const half8*)(lds + dbuf + boffB[nf] + blkoff0);
      bb[nf][1] = *(const half8*)(lds + dbuf + boffB[nf] + blkoff1);
    }
    if (u <= 13) stageA(0, u + 2);
    PHASE_TAIL()
#pragma unroll
    for (int ii = 0; ii < 4; ++ii)
#pragma unroll
      for (int nf = 2; nf < 4; ++nf) {
        acc[ii][nf] = __builtin_amdgcn_mfma_f32_16x16x32_f16(a[ii][0], bb[nf][0], acc[ii][nf], 0, 0, 0);
        acc[ii][nf] = __builtin_amdgcn_mfma_f32_16x16x32_f16(a[ii][1], bb[nf][1], acc[ii][nf], 0, 0, 0);
      }
    PHASE_END()

    // ---- P3: read A q1; stage Bs0(u+2); quad (mi=1, n=0..1), bb[0..1] live
#pragma unroll
    for (int ii = 0; ii < 4; ++ii) {
      a[ii][0] = *(const half8*)(lds + dbuf + 16384 + aoffA[ii] + blkoff0);
      a[ii][1] = *(const half8*)(lds + dbuf + 16384 + aoffA[ii] + blkoff1);
    }
    if (u <= 13) stageB(0, u + 2);
    PHASE_TAIL()
#pragma unroll
    for (int ii = 0; ii < 4; ++ii)
#pragma unroll
      for (int nf = 0; nf < 2; ++nf) {
        acc[4 + ii][nf] = __builtin_amdgcn_mfma_f32_16x16x32_f16(a[ii][0], bb[nf][0], acc[4 + ii][nf], 0, 0, 0);
        acc[4 + ii][nf] = __builtin_amdgcn_mfma_f32_16x16x32_f16(a[ii][1], bb[nf][1], acc[4 + ii][nf], 0, 0, 0);
      }
    PHASE_END()

    // ---- P4: no reads; stage Aq1(u+2); counted vmcnt; quad (mi=1, n=2..3)
    if (u <= 13) stageA(1, u + 2);
    if (u < 14) {
      asm volatile("s_waitcnt vmcnt(6)" ::: "memory");
    } else if (u == 14) {
      asm volatile("s_waitcnt vmcnt(0)" ::: "memory");
    }
    PHASE_TAIL()
#pragma unroll
    for (int ii = 0; ii < 4; ++ii)
#pragma unroll
      for (int nf = 2; nf < 4; ++nf) {
        acc[4 + ii][nf] = __builtin_amdgcn_mfma_f32_16x16x32_f16(a[ii][0], bb[nf][0], acc[4 + ii][nf], 0, 0, 0);
        acc[4 + ii][nf] = __builtin_amdgcn_mfma_f32_16x16x32_f16(a[ii][1], bb[nf][1], acc[4 + ii][nf], 0, 0, 0);
      }
    PHASE_END()
  }
#undef PHASE_TAIL
#undef PHASE_END

  // epilogue: m = 4h+gate; lane-group lg holds gates 0..3 of h = (mbase>>2)+lg
#pragma unroll
  for (int i = 0; i < 8; ++i) {
    int h = ((m0 + wr * 128 + i * 16) >> 2) + lg;
    float vbz = bz[h], vbf = bf[h], vbo = bo[h], vbi = bi[h];
#pragma unroll
    for (int j = 0; j < 4; ++j) {
      int t = t0 + wc * 64 + j * 16 + l15;
      float yz = acc[i][j][0] + vbz;
      float yf = acc[i][j][1] + vbf;
      float yo = acc[i][j][2] + vbo;
      float yi = acc[i][j][3] + vbi;
      float zz = tanhf(yz);
      float ff = sigmoidf_(yf);
      float oo = sigmoidf_(yo);
      float ii2 = sigmoidf_(yi);
      size_t gi = ((size_t)b * H_DIM + h) * T_DIM + t;
      F[gi] = (_Float16)ff;
      G[gi] = (_Float16)(ii2 * zz);
      O[gi] = (_Float16)oo;
    }
  }
}

// ---------------------------------------------------------------------------
// K3: fused scan. One block per (b,h) row (4096 blocks x 256 threads).
// ---------------------------------------------------------------------------
__global__ __launch_bounds__(256) void scan_fused(
    const _Float16* __restrict__ F, const _Float16* __restrict__ G,
    const _Float16* __restrict__ O, float* __restrict__ out) {
  __shared__ char smem[24 * 1024 + 64];
  _Float16* sF = (_Float16*)smem;              // 8KB: 512 16B-blocks
  _Float16* sG = (_Float16*)(smem + 8192);
  _Float16* sO = (_Float16*)(smem + 16384);
  float* sOut = (float*)smem;                  // 16KB, aliases sF+sG
  float* wFs = (float*)(smem + 24576);
  float* wGs = wFs + 4;

  int tid = threadIdx.x;
  int lane = tid & 63, wv = tid >> 6;
  size_t base = (size_t)blockIdx.x * T_DIM;
  const _Float16* Fg = F + base;
  const _Float16* Gg = G + base;
  const _Float16* Og = O + base;

#pragma unroll
  for (int it = 0; it < 2; ++it) {
    int idx = it * 256 + tid;
    int sb = idx ^ ((idx >> 3) & 7);
    gload16(Fg + sb * 8, (char*)sF + idx * 16);
    gload16(Gg + sb * 8, (char*)sG + idx * 16);
    gload16(Og + sb * 8, (char*)sO + idx * 16);
  }
  asm volatile("s_waitcnt vmcnt(0)" ::: "memory");
  __syncthreads();

  int i = tid;
  int b0 = (2 * i) ^ (((2 * i) >> 3) & 7);
  int b1 = (2 * i + 1) ^ (((2 * i + 1) >> 3) & 7);
  half8 f0 = *(half8*)((char*)sF + b0 * 16);
  half8 f1 = *(half8*)((char*)sF + b1 * 16);
  half8 g0 = *(half8*)((char*)sG + b0 * 16);
  half8 g1 = *(half8*)((char*)sG + b1 * 16);
  half8 o0 = *(half8*)((char*)sO + b0 * 16);
  half8 o1 = *(half8*)((char*)sO + b1 * 16);

  float Fp = 1.f, Gc = 0.f;
#pragma unroll
  for (int e = 0; e < 8; ++e) {
    float fe = (float)f0[e];
    Gc = fe * Gc + (float)g0[e];
    Fp *= fe;
  }
#pragma unroll
  for (int e = 0; e < 8; ++e) {
    float fe = (float)f1[e];
    Gc = fe * Gc + (float)g1[e];
    Fp *= fe;
  }

  float Fs = Fp, Gs = Gc;
#pragma unroll
  for (int d = 1; d < 64; d <<= 1) {
    float Fo = __shfl_up(Fs, d);
    float Go = __shfl_up(Gs, d);
    if (lane >= d) { Gs = Fs * Go + Gs; Fs = Fs * Fo; }
  }
  if (lane == 63) { wFs[wv] = Fs; wGs[wv] = Gs; }
  __syncthreads();
  float carry = 0.f;
  for (int w = 0; w < wv; ++w) carry = wFs[w] * carry + wGs[w];
  float Fpr = __shfl_up(Fs, 1);
  float Gpr = __shfl_up(Gs, 1);
  float cin = (lane == 0) ? carry : Fpr * carry + Gpr;

  float c = cin;
  float4 r0, r1, r2, r3;
#define QSTEP(fv, gv, ov, e, dst) \
  { c = (float)fv[e] * c + (float)gv[e]; dst = (float)ov[e] * c; }
  QSTEP(f0, g0, o0, 0, r0.x) QSTEP(f0, g0, o0, 1, r0.y)
  QSTEP(f0, g0, o0, 2, r0.z) QSTEP(f0, g0, o0, 3, r0.w)
  QSTEP(f0, g0, o0, 4, r1.x) QSTEP(f0, g0, o0, 5, r1.y)
  QSTEP(f0, g0, o0, 6, r1.z) QSTEP(f0, g0, o0, 7, r1.w)
  QSTEP(f1, g1, o1, 0, r2.x) QSTEP(f1, g1, o1, 1, r2.y)
  QSTEP(f1, g1, o1, 2, r2.z) QSTEP(f1, g1, o1, 3, r2.w)
  QSTEP(f1, g1, o1, 4, r3.x) QSTEP(f1, g1, o1, 5, r3.y)
  QSTEP(f1, g1, o1, 6, r3.z) QSTEP(f1, g1, o1, 7, r3.w)
#undef QSTEP
  {
    int obl = 4 * i;
    int s0 = (obl + 0) ^ (((obl + 0) >> 3) & 7);
    int s1 = (obl + 1) ^ (((obl + 1) >> 3) & 7);
    int s2 = (obl + 2) ^ (((obl + 2) >> 3) & 7);
    int s3 = (obl + 3) ^ (((obl + 3) >> 3) & 7);
    *(float4*)((char*)sOut + s0 * 16) = r0;
    *(float4*)((char*)sOut + s1 * 16) = r1;
    *(float4*)((char*)sOut + s2 * 16) = r2;
    *(float4*)((char*)sOut + s3 * 16) = r3;
  }
  __syncthreads();

  float* og = out + base;
#pragma unroll
  for (int it = 0; it < 4; ++it) {
    int idx = it * 256 + tid;
    int sb = idx ^ ((idx >> 3) & 7);
    *(float4*)(og + idx * 4) = *(float4*)((char*)sOut + sb * 16);
  }
}

// ---------------------------------------------------------------------------
extern "C" void kernel_launch(void* const* d_in, const int* in_sizes, int n_in,
                              void* d_out, int out_size, void* d_ws, size_t ws_size,
                              hipStream_t stream) {
  (void)in_sizes; (void)n_in; (void)out_size; (void)ws_size;
  const float* x  = (const float*)d_in[0];
  const float* wz = (const float*)d_in[1];
  const float* bz = (const float*)d_in[2];
  const float* wf = (const float*)d_in[3];
  const float* bf = (const float*)d_in[4];
  const float* wo = (const float*)d_in[5];
  const float* bo = (const float*)d_in[6];
  const float* wi = (const float*)d_in[7];
  const float* bi = (const float*)d_in[8];

  char* ws = (char*)d_ws;
  const size_t MB = 1ull << 20;
  _Float16* A16 = (_Float16*)(ws);                 //   4 MB
  _Float16* XTg = (_Float16*)(ws + 4 * MB);        //  ~32.01 MB  [B][T+1][512]
  _Float16* F   = (_Float16*)(ws + 40 * MB);       //  32 MB
  _Float16* G   = (_Float16*)(ws + 72 * MB);       //  32 MB
  _Float16* O   = (_Float16*)(ws + 104 * MB);      //  32 MB

  hipFuncSetAttribute((const void*)qrnn_gemm2,
                      hipFuncAttributeMaxDynamicSharedMemorySize, 131072);

  pack_w<<<(MTOT * KTOT) / 256, 256, 0, stream>>>(wz, wf, wo, wi, A16);
  transpose_x<<<B_DIM * 8 * 64, 256, 0, stream>>>(x, XTg);
  qrnn_gemm2<<<B_DIM * 8 * 16, 512, 131072, stream>>>(A16, XTg, bz, bf, bo, bi, F, G, O);
  scan_fused<<<B_DIM * H_DIM, 256, 0, stream>>>(F, G, O, (float*)d_out);
}

// Round 5
// 327.117 us; speedup vs baseline: 1.0073x; 1.0053x over previous
//
#include <hip/hip_runtime.h>
#include <hip/hip_bf16.h>
#include <cstdint>

typedef _Float16 half8 __attribute__((ext_vector_type(8)));
typedef float f32x4 __attribute__((ext_vector_type(4)));

#define B_DIM 8
#define C_DIM 512
#define H_DIM 512
#define T_DIM 4096
#define KTOT 1024   // 2*C
#define MTOT 2048   // 4*H, interleaved m = 4*h + gate (z,f,o,i)

__device__ __forceinline__ void gload16(const void* g, void* l) {
  __builtin_amdgcn_global_load_lds(
      (const __attribute__((address_space(1))) unsigned int*)g,
      (__attribute__((address_space(3))) unsigned int*)l, 16, 0, 0);
}

__device__ __forceinline__ float sigmoidf_(float x) { return 1.0f / (1.0f + expf(-x)); }

// ---------------------------------------------------------------------------
// K0: merged prep.
//  bid < 4096: transpose+convert x fp32 [B][C][T] -> XTg fp16 [B][T+1][512]
//              (row 0 per b zeroed guard = t(-1); XTg[b][1+t][c] = x[b][c][t])
//  bid >= 4096: pack weights fp32 [H][C][2] -> fp16 A16[m=4h+g][k=j*512+c]
//              one float2 read per thread -> both K-planes (coalesced).
// ---------------------------------------------------------------------------
__global__ __launch_bounds__(256) void prep(
    const float* __restrict__ x,
    const float* __restrict__ wz, const float* __restrict__ wf,
    const float* __restrict__ wo, const float* __restrict__ wi,
    _Float16* __restrict__ XTg, _Float16* __restrict__ A16) {
  __shared__ _Float16 tile[64][73];   // odd stride -> conflict-free transpose
  int bid = blockIdx.x;
  int tid = threadIdx.x;
  if (bid < 4096) {
    int b = bid >> 9;
    int rem = bid & 511;
    int c0 = (rem >> 6) * 64;
    int t0 = (rem & 63) * 64;
#pragma unroll
    for (int it = 0; it < 4; ++it) {
      int idx = it * 256 + tid;      // 1024 tasks: 64 c-rows x 16 float4
      int ci = idx >> 4, tc = idx & 15;
      float4 v = *(const float4*)(x + (((size_t)b * C_DIM + c0 + ci) * T_DIM + t0 + tc * 4));
      tile[ci][tc * 4 + 0] = (_Float16)v.x;
      tile[ci][tc * 4 + 1] = (_Float16)v.y;
      tile[ci][tc * 4 + 2] = (_Float16)v.z;
      tile[ci][tc * 4 + 3] = (_Float16)v.w;
    }
    __syncthreads();
#pragma unroll
    for (int it = 0; it < 2; ++it) {
      int idx = it * 256 + tid;      // 512 tasks: 64 t-rows x 8 c-blocks
      int tr = idx >> 3, cb = idx & 7;
      half8 h;
#pragma unroll
      for (int e = 0; e < 8; ++e) h[e] = tile[cb * 8 + e][tr];
      int t = t0 + tr;
      *(half8*)(XTg + ((size_t)b * (T_DIM + 1) + 1 + t) * 512 + c0 + cb * 8) = h;
    }
    if (t0 == 0 && tid < 8) {        // zero guard row (t = -1)
      half8 z = {};
      *(half8*)(XTg + ((size_t)b * (T_DIM + 1)) * 512 + c0 + tid * 8) = z;
    }
  } else {
    int idx = (bid - 4096) * 256 + tid;   // [0, 2048*512)
    int m = idx >> 9, c = idx & 511;
    int h = m >> 2, g = m & 3;
    const float* w = (g == 0) ? wz : (g == 1) ? wf : (g == 2) ? wo : wi;
    float2 v = *(const float2*)(w + (h << 10) + (c << 1));
    A16[(size_t)m * KTOT + c] = (_Float16)v.x;        // j=0 plane (pairs x[t-1])
    A16[(size_t)m * KTOT + 512 + c] = (_Float16)v.y;  // j=1 plane (pairs x[t])
  }
}

// ---------------------------------------------------------------------------
// K2: GEMM Y[2048, T] = A16[2048,1024] @ XTg^T-expanded, fused activations.
//     Proven r1 structure: 128x128 tile, BK=64, 4 waves (2x2),
//     mfma_f32_16x16x32_f16, gload_lds w16, XOR-swizzled 16B blocks.
//     B operand row t, k: k<512 -> XTg[b][t][k] (x[t-1] via guard),
//                         k>=512 -> XTg[b][t+1][k-512] (x[t]).
//     XCD swizzle: one b per XCD (4096%8==0, bijective), m-outer t-inner.
// ---------------------------------------------------------------------------
__global__ __launch_bounds__(256, 4) void qrnn_gemm(
    const _Float16* __restrict__ A16, const _Float16* __restrict__ XTg,
    const float* __restrict__ bz, const float* __restrict__ bf,
    const float* __restrict__ bo, const float* __restrict__ bi,
    _Float16* __restrict__ F, _Float16* __restrict__ G, _Float16* __restrict__ O) {
  __shared__ _Float16 lA[128 * 64];
  __shared__ _Float16 lB[128 * 64];
  int bid = blockIdx.x;                       // 4096 = 8b * 16m * 32t
  int gbid = (bid & 7) * 512 + (bid >> 3);    // XCD-contiguous chunks
  int b = gbid >> 9;                          // one b per XCD
  int rem = gbid & 511;
  int m0 = (rem >> 5) * 128;                  // m-outer: A slab (512KB) L2-hot
  int t0 = (rem & 31) * 128;                  // t-inner: B streams
  int tid = threadIdx.x;
  int lane = tid & 63, wid = tid >> 6;
  int wm = (wid >> 1) * 64, wn = (wid & 1) * 64;

  f32x4 acc[4][4];
#pragma unroll
  for (int i = 0; i < 4; ++i)
#pragma unroll
    for (int j = 0; j < 4; ++j) acc[i][j] = (f32x4){0.f, 0.f, 0.f, 0.f};

  const _Float16* Ab = A16 + (size_t)m0 * KTOT;
  const _Float16* Bb = XTg + ((size_t)b * (T_DIM + 1) + 1 + t0) * 512;  // x[t0] row

  for (int kt = 0; kt < 16; ++kt) {
    int k0 = kt * 64;
    int cp = k0 & 511;
    int jofs = (k0 < 512) ? 512 : 0;          // j=0 plane reads row t-1
    // stage A and B tiles: [128 rows][64 halves], XOR-swizzled 16B blocks.
    // LDS dest linear (idx*16); global source block = blk ^ (row&7).
#pragma unroll
    for (int it = 0; it < 4; ++it) {
      int idx = it * 256 + tid;
      int row = idx >> 3, blk = idx & 7;
      int gblk = blk ^ (row & 7);
      gload16(Ab + (size_t)row * KTOT + k0 + gblk * 8, (char*)lA + idx * 16);
    }
#pragma unroll
    for (int it = 0; it < 4; ++it) {
      int idx = it * 256 + tid;
      int row = idx >> 3, blk = idx & 7;
      int gblk = blk ^ (row & 7);
      gload16(Bb + (size_t)(row * 512) - jofs + cp + gblk * 8, (char*)lB + idx * 16);
    }
    __syncthreads();
#pragma unroll
    for (int ks = 0; ks < 2; ++ks) {
      half8 av[4], bv[4];
#pragma unroll
      for (int i = 0; i < 4; ++i) {
        int row = wm + i * 16 + (lane & 15);
        int blk = (ks * 4 + (lane >> 4)) ^ (row & 7);
        av[i] = *(const half8*)(lA + row * 64 + blk * 8);
      }
#pragma unroll
      for (int j = 0; j < 4; ++j) {
        int row = wn + j * 16 + (lane & 15);
        int blk = (ks * 4 + (lane >> 4)) ^ (row & 7);
        bv[j] = *(const half8*)(lB + row * 64 + blk * 8);
      }
#pragma unroll
      for (int i = 0; i < 4; ++i)
#pragma unroll
        for (int j = 0; j < 4; ++j)
          acc[i][j] = __builtin_amdgcn_mfma_f32_16x16x32_f16(av[i], bv[j], acc[i][j], 0, 0, 0);
    }
    __syncthreads();
  }

  // epilogue: rows m = 4h+gate; lane group (lane>>4) holds gates 0..3 of one h.
#pragma unroll
  for (int i = 0; i < 4; ++i) {
    int h = ((m0 + wm + i * 16) >> 2) + (lane >> 4);
    float vbz = bz[h], vbf = bf[h], vbo = bo[h], vbi = bi[h];
#pragma unroll
    for (int j = 0; j < 4; ++j) {
      int t = t0 + wn + j * 16 + (lane & 15);
      float yz = acc[i][j][0] + vbz;
      float yf = acc[i][j][1] + vbf;
      float yo = acc[i][j][2] + vbo;
      float yi = acc[i][j][3] + vbi;
      float zz = tanhf(yz);
      float ff = sigmoidf_(yf);
      float oo = sigmoidf_(yo);
      float ii = sigmoidf_(yi);
      size_t gi = ((size_t)b * H_DIM + h) * T_DIM + t;
      F[gi] = (_Float16)ff;
      G[gi] = (_Float16)(ii * zz);
      O[gi] = (_Float16)oo;
    }
  }
}

// ---------------------------------------------------------------------------
// K3: fused scan. One block per (b,h) row (4096 blocks x 256 threads).
//     Stage F,G,O (24KB) -> LDS via gload_lds (swizzled source), per-thread
//     16-elem register scan, block-scan via shuffles, swizzled-LDS writeback.
// ---------------------------------------------------------------------------
__global__ __launch_bounds__(256) void scan_fused(
    const _Float16* __restrict__ F, const _Float16* __restrict__ G,
    const _Float16* __restrict__ O, float* __restrict__ out) {
  __shared__ char smem[24 * 1024 + 64];
  _Float16* sF = (_Float16*)smem;              // 8KB: 512 16B-blocks
  _Float16* sG = (_Float16*)(smem + 8192);
  _Float16* sO = (_Float16*)(smem + 16384);
  float* sOut = (float*)smem;                  // 16KB, aliases sF+sG
  float* wFs = (float*)(smem + 24576);
  float* wGs = wFs + 4;

  int tid = threadIdx.x;
  int lane = tid & 63, wv = tid >> 6;
  size_t base = (size_t)blockIdx.x * T_DIM;
  const _Float16* Fg = F + base;
  const _Float16* Gg = G + base;
  const _Float16* Og = O + base;

#pragma unroll
  for (int it = 0; it < 2; ++it) {
    int idx = it * 256 + tid;
    int sb = idx ^ ((idx >> 3) & 7);
    gload16(Fg + sb * 8, (char*)sF + idx * 16);
    gload16(Gg + sb * 8, (char*)sG + idx * 16);
    gload16(Og + sb * 8, (char*)sO + idx * 16);
  }
  asm volatile("s_waitcnt vmcnt(0)" ::: "memory");
  __syncthreads();

  int i = tid;
  int b0 = (2 * i) ^ (((2 * i) >> 3) & 7);
  int b1 = (2 * i + 1) ^ (((2 * i + 1) >> 3) & 7);
  half8 f0 = *(half8*)((char*)sF + b0 * 16);
  half8 f1 = *(half8*)((char*)sF + b1 * 16);
  half8 g0 = *(half8*)((char*)sG + b0 * 16);
  half8 g1 = *(half8*)((char*)sG + b1 * 16);
  half8 o0 = *(half8*)((char*)sO + b0 * 16);
  half8 o1 = *(half8*)((char*)sO + b1 * 16);

  float Fp = 1.f, Gc = 0.f;
#pragma unroll
  for (int e = 0; e < 8; ++e) {
    float fe = (float)f0[e];
    Gc = fe * Gc + (float)g0[e];
    Fp *= fe;
  }
#pragma unroll
  for (int e = 0; e < 8; ++e) {
    float fe = (float)f1[e];
    Gc = fe * Gc + (float)g1[e];
    Fp *= fe;
  }

  float Fs = Fp, Gs = Gc;
#pragma unroll
  for (int d = 1; d < 64; d <<= 1) {
    float Fo = __shfl_up(Fs, d);
    float Go = __shfl_up(Gs, d);
    if (lane >= d) { Gs = Fs * Go + Gs; Fs = Fs * Fo; }
  }
  if (lane == 63) { wFs[wv] = Fs; wGs[wv] = Gs; }
  __syncthreads();
  float carry = 0.f;
  for (int w = 0; w < wv; ++w) carry = wFs[w] * carry + wGs[w];
  float Fpr = __shfl_up(Fs, 1);
  float Gpr = __shfl_up(Gs, 1);
  float cin = (lane == 0) ? carry : Fpr * carry + Gpr;

  float c = cin;
  float4 r0, r1, r2, r3;
#define QSTEP(fv, gv, ov, e, dst) \
  { c = (float)fv[e] * c + (float)gv[e]; dst = (float)ov[e] * c; }
  QSTEP(f0, g0, o0, 0, r0.x) QSTEP(f0, g0, o0, 1, r0.y)
  QSTEP(f0, g0, o0, 2, r0.z) QSTEP(f0, g0, o0, 3, r0.w)
  QSTEP(f0, g0, o0, 4, r1.x) QSTEP(f0, g0, o0, 5, r1.y)
  QSTEP(f0, g0, o0, 6, r1.z) QSTEP(f0, g0, o0, 7, r1.w)
  QSTEP(f1, g1, o1, 0, r2.x) QSTEP(f1, g1, o1, 1, r2.y)
  QSTEP(f1, g1, o1, 2, r2.z) QSTEP(f1, g1, o1, 3, r2.w)
  QSTEP(f1, g1, o1, 4, r3.x) QSTEP(f1, g1, o1, 5, r3.y)
  QSTEP(f1, g1, o1, 6, r3.z) QSTEP(f1, g1, o1, 7, r3.w)
#undef QSTEP
  {
    int obl = 4 * i;
    int s0 = (obl + 0) ^ (((obl + 0) >> 3) & 7);
    int s1 = (obl + 1) ^ (((obl + 1) >> 3) & 7);
    int s2 = (obl + 2) ^ (((obl + 2) >> 3) & 7);
    int s3 = (obl + 3) ^ (((obl + 3) >> 3) & 7);
    *(float4*)((char*)sOut + s0 * 16) = r0;
    *(float4*)((char*)sOut + s1 * 16) = r1;
    *(float4*)((char*)sOut + s2 * 16) = r2;
    *(float4*)((char*)sOut + s3 * 16) = r3;
  }
  __syncthreads();

  float* og = out + base;
#pragma unroll
  for (int it = 0; it < 4; ++it) {
    int idx = it * 256 + tid;
    int sb = idx ^ ((idx >> 3) & 7);
    *(float4*)(og + idx * 4) = *(float4*)((char*)sOut + sb * 16);
  }
}

// ---------------------------------------------------------------------------
extern "C" void kernel_launch(void* const* d_in, const int* in_sizes, int n_in,
                              void* d_out, int out_size, void* d_ws, size_t ws_size,
                              hipStream_t stream) {
  (void)in_sizes; (void)n_in; (void)out_size; (void)ws_size;
  const float* x  = (const float*)d_in[0];
  const float* wz = (const float*)d_in[1];
  const float* bz = (const float*)d_in[2];
  const float* wf = (const float*)d_in[3];
  const float* bf = (const float*)d_in[4];
  const float* wo = (const float*)d_in[5];
  const float* bo = (const float*)d_in[6];
  const float* wi = (const float*)d_in[7];
  const float* bi = (const float*)d_in[8];

  char* ws = (char*)d_ws;
  const size_t MB = 1ull << 20;
  _Float16* A16 = (_Float16*)(ws);                 //   4 MB
  _Float16* XTg = (_Float16*)(ws + 4 * MB);        //  ~32.01 MB  [B][T+1][512]
  _Float16* F   = (_Float16*)(ws + 40 * MB);       //  32 MB
  _Float16* G   = (_Float16*)(ws + 72 * MB);       //  32 MB
  _Float16* O   = (_Float16*)(ws + 104 * MB);      //  32 MB

  prep<<<4096 + 4096, 256, 0, stream>>>(x, wz, wf, wo, wi, XTg, A16);
  qrnn_gemm<<<B_DIM * 16 * 32, 256, 0, stream>>>(A16, XTg, bz, bf, bo, bi, F, G, O);
  scan_fused<<<B_DIM * H_DIM, 256, 0, stream>>>(F, G, O, (float*)d_out);
}

// Round 6
// 317.907 us; speedup vs baseline: 1.0364x; 1.0290x over previous
//
#include <hip/hip_runtime.h>
#include <hip/hip_bf16.h>
#include <cstdint>

typedef _Float16 half8 __attribute__((ext_vector_type(8)));
typedef float f32x4 __attribute__((ext_vector_type(4)));

#define B_DIM 8
#define C_DIM 512
#define H_DIM 512
#define T_DIM 4096
#define KTOT 1024   // 2*C
#define MTOT 2048   // 4*H, interleaved m = 4*h + gate (z,f,o,i)

__device__ __forceinline__ void gload16(const void* g, void* l) {
  __builtin_amdgcn_global_load_lds(
      (const __attribute__((address_space(1))) unsigned int*)g,
      (__attribute__((address_space(3))) unsigned int*)l, 16, 0, 0);
}

__device__ __forceinline__ float sigmoidf_(float x) { return 1.0f / (1.0f + expf(-x)); }

// ---------------------------------------------------------------------------
// K0: merged prep.
//  bid < 4096: transpose+convert x fp32 [B][C][T] -> XTg fp16 [B][T+1][512]
//              (row 0 per b zeroed guard = t(-1); XTg[b][1+t][c] = x[b][c][t])
//  bid >= 4096: pack weights fp32 [H][C][2] -> fp16 A16[m=4h+g][k=j*512+c]
// ---------------------------------------------------------------------------
__global__ __launch_bounds__(256) void prep(
    const float* __restrict__ x,
    const float* __restrict__ wz, const float* __restrict__ wf,
    const float* __restrict__ wo, const float* __restrict__ wi,
    _Float16* __restrict__ XTg, _Float16* __restrict__ A16) {
  __shared__ _Float16 tile[64][73];   // odd stride -> conflict-free transpose
  int bid = blockIdx.x;
  int tid = threadIdx.x;
  if (bid < 4096) {
    int b = bid >> 9;
    int rem = bid & 511;
    int c0 = (rem >> 6) * 64;
    int t0 = (rem & 63) * 64;
#pragma unroll
    for (int it = 0; it < 4; ++it) {
      int idx = it * 256 + tid;      // 1024 tasks: 64 c-rows x 16 float4
      int ci = idx >> 4, tc = idx & 15;
      float4 v = *(const float4*)(x + (((size_t)b * C_DIM + c0 + ci) * T_DIM + t0 + tc * 4));
      tile[ci][tc * 4 + 0] = (_Float16)v.x;
      tile[ci][tc * 4 + 1] = (_Float16)v.y;
      tile[ci][tc * 4 + 2] = (_Float16)v.z;
      tile[ci][tc * 4 + 3] = (_Float16)v.w;
    }
    __syncthreads();
#pragma unroll
    for (int it = 0; it < 2; ++it) {
      int idx = it * 256 + tid;      // 512 tasks: 64 t-rows x 8 c-blocks
      int tr = idx >> 3, cb = idx & 7;
      half8 h;
#pragma unroll
      for (int e = 0; e < 8; ++e) h[e] = tile[cb * 8 + e][tr];
      int t = t0 + tr;
      *(half8*)(XTg + ((size_t)b * (T_DIM + 1) + 1 + t) * 512 + c0 + cb * 8) = h;
    }
    if (t0 == 0 && tid < 8) {        // zero guard row (t = -1)
      half8 z = {};
      *(half8*)(XTg + ((size_t)b * (T_DIM + 1)) * 512 + c0 + tid * 8) = z;
    }
  } else {
    int idx = (bid - 4096) * 256 + tid;   // [0, 2048*512)
    int m = idx >> 9, c = idx & 511;
    int h = m >> 2, g = m & 3;
    const float* w = (g == 0) ? wz : (g == 1) ? wf : (g == 2) ? wo : wi;
    float2 v = *(const float2*)(w + (h << 10) + (c << 1));
    A16[(size_t)m * KTOT + c] = (_Float16)v.x;        // j=0 plane (pairs x[t-1])
    A16[(size_t)m * KTOT + 512 + c] = (_Float16)v.y;  // j=1 plane (pairs x[t])
  }
}

// ---------------------------------------------------------------------------
// K2: GEMM Y[2048, T] = A16 @ XTg^T-expanded, fused activations.
//     EXACT r1 config: 128x128 tile, BK=64, 4 waves (2x2), launch_bounds(256,2),
//     natural bid order (no XCD swizzle), mfma_f32_16x16x32_f16,
//     gload_lds w16, XOR-swizzled 16B blocks.
//     B operand row t, k: k<512 -> x[t-1] (XTg row t0+row via guard),
//                         k>=512 -> x[t] (XTg row 1+t0+row).
//     Outputs fp16 FGO[bh][3][T]: f,g,o interleaved per (b,h) row so the
//     scan reads one contiguous 24KB window (kills 32MB power-of-2 aliasing).
// ---------------------------------------------------------------------------
__global__ __launch_bounds__(256, 2) void qrnn_gemm(
    const _Float16* __restrict__ A16, const _Float16* __restrict__ XTg,
    const float* __restrict__ bz, const float* __restrict__ bf,
    const float* __restrict__ bo, const float* __restrict__ bi,
    _Float16* __restrict__ FGO) {
  __shared__ _Float16 lA[128 * 64];
  __shared__ _Float16 lB[128 * 64];
  int bid = blockIdx.x;                 // 4096 = 8b * 16m * 32t, natural order
  int b = bid >> 9;
  int rem = bid & 511;
  int m0 = (rem >> 5) * 128;
  int t0 = (rem & 31) * 128;
  int tid = threadIdx.x;
  int lane = tid & 63, wid = tid >> 6;
  int wm = (wid >> 1) * 64, wn = (wid & 1) * 64;

  f32x4 acc[4][4];
#pragma unroll
  for (int i = 0; i < 4; ++i)
#pragma unroll
    for (int j = 0; j < 4; ++j) acc[i][j] = (f32x4){0.f, 0.f, 0.f, 0.f};

  const _Float16* Ab = A16 + (size_t)m0 * KTOT;
  const _Float16* Bb = XTg + ((size_t)b * (T_DIM + 1) + 1 + t0) * 512;  // x[t0] row

  for (int kt = 0; kt < 16; ++kt) {
    int k0 = kt * 64;
    int cp = k0 & 511;
    int jofs = (k0 < 512) ? 512 : 0;          // j=0 plane reads row t-1
#pragma unroll
    for (int it = 0; it < 4; ++it) {
      int idx = it * 256 + tid;
      int row = idx >> 3, blk = idx & 7;
      int gblk = blk ^ (row & 7);
      gload16(Ab + (size_t)row * KTOT + k0 + gblk * 8, (char*)lA + idx * 16);
    }
#pragma unroll
    for (int it = 0; it < 4; ++it) {
      int idx = it * 256 + tid;
      int row = idx >> 3, blk = idx & 7;
      int gblk = blk ^ (row & 7);
      gload16(Bb + (size_t)(row * 512) - jofs + cp + gblk * 8, (char*)lB + idx * 16);
    }
    __syncthreads();
#pragma unroll
    for (int ks = 0; ks < 2; ++ks) {
      half8 av[4], bv[4];
#pragma unroll
      for (int i = 0; i < 4; ++i) {
        int row = wm + i * 16 + (lane & 15);
        int blk = (ks * 4 + (lane >> 4)) ^ (row & 7);
        av[i] = *(const half8*)(lA + row * 64 + blk * 8);
      }
#pragma unroll
      for (int j = 0; j < 4; ++j) {
        int row = wn + j * 16 + (lane & 15);
        int blk = (ks * 4 + (lane >> 4)) ^ (row & 7);
        bv[j] = *(const half8*)(lB + row * 64 + blk * 8);
      }
#pragma unroll
      for (int i = 0; i < 4; ++i)
#pragma unroll
        for (int j = 0; j < 4; ++j)
          acc[i][j] = __builtin_amdgcn_mfma_f32_16x16x32_f16(av[i], bv[j], acc[i][j], 0, 0, 0);
    }
    __syncthreads();
  }

  // epilogue: rows m = 4h+gate; lane group (lane>>4) holds gates 0..3 of one h.
#pragma unroll
  for (int i = 0; i < 4; ++i) {
    int h = ((m0 + wm + i * 16) >> 2) + (lane >> 4);
    float vbz = bz[h], vbf = bf[h], vbo = bo[h], vbi = bi[h];
    size_t rowbase = ((size_t)b * H_DIM + h) * (3 * T_DIM);
#pragma unroll
    for (int j = 0; j < 4; ++j) {
      int t = t0 + wn + j * 16 + (lane & 15);
      float yz = acc[i][j][0] + vbz;
      float yf = acc[i][j][1] + vbf;
      float yo = acc[i][j][2] + vbo;
      float yi = acc[i][j][3] + vbi;
      float zz = tanhf(yz);
      float ff = sigmoidf_(yf);
      float oo = sigmoidf_(yo);
      float ii = sigmoidf_(yi);
      FGO[rowbase + t] = (_Float16)ff;                     // f plane
      FGO[rowbase + T_DIM + t] = (_Float16)(ii * zz);      // g plane
      FGO[rowbase + 2 * T_DIM + t] = (_Float16)oo;         // o plane
    }
  }
}

// ---------------------------------------------------------------------------
// K3: fused scan. One block per (b,h) row (4096 blocks x 256 threads).
//     Stage contiguous 24KB FGO row -> LDS via gload_lds (swizzled source),
//     per-thread 16-elem register scan, block-scan via shuffles, swizzled-LDS
//     staged coalesced float4 writeback.
// ---------------------------------------------------------------------------
__global__ __launch_bounds__(256) void scan_fused(
    const _Float16* __restrict__ FGO, float* __restrict__ out) {
  __shared__ char smem[24 * 1024 + 64];
  _Float16* sF = (_Float16*)smem;              // 8KB: 512 16B-blocks
  _Float16* sG = (_Float16*)(smem + 8192);
  _Float16* sO = (_Float16*)(smem + 16384);
  float* sOut = (float*)smem;                  // 16KB, aliases sF+sG
  float* wFs = (float*)(smem + 24576);
  float* wGs = wFs + 4;

  int tid = threadIdx.x;
  int lane = tid & 63, wv = tid >> 6;
  const _Float16* src = FGO + (size_t)blockIdx.x * (3 * T_DIM);

  // stage 24KB contiguous: 1536 16B-blocks; swizzle stays inside 128B windows
#pragma unroll
  for (int it = 0; it < 6; ++it) {
    int idx = it * 256 + tid;
    int sb = idx ^ ((idx >> 3) & 7);
    gload16(src + sb * 8, smem + idx * 16);
  }
  asm volatile("s_waitcnt vmcnt(0)" ::: "memory");
  __syncthreads();

  int i = tid;
  int b0 = (2 * i) ^ (((2 * i) >> 3) & 7);
  int b1 = (2 * i + 1) ^ (((2 * i + 1) >> 3) & 7);
  half8 f0 = *(half8*)((char*)sF + b0 * 16);
  half8 f1 = *(half8*)((char*)sF + b1 * 16);
  half8 g0 = *(half8*)((char*)sG + b0 * 16);
  half8 g1 = *(half8*)((char*)sG + b1 * 16);
  half8 o0 = *(half8*)((char*)sO + b0 * 16);
  half8 o1 = *(half8*)((char*)sO + b1 * 16);

  float Fp = 1.f, Gc = 0.f;
#pragma unroll
  for (int e = 0; e < 8; ++e) {
    float fe = (float)f0[e];
    Gc = fe * Gc + (float)g0[e];
    Fp *= fe;
  }
#pragma unroll
  for (int e = 0; e < 8; ++e) {
    float fe = (float)f1[e];
    Gc = fe * Gc + (float)g1[e];
    Fp *= fe;
  }

  float Fs = Fp, Gs = Gc;
#pragma unroll
  for (int d = 1; d < 64; d <<= 1) {
    float Fo = __shfl_up(Fs, d);
    float Go = __shfl_up(Gs, d);
    if (lane >= d) { Gs = Fs * Go + Gs; Fs = Fs * Fo; }
  }
  if (lane == 63) { wFs[wv] = Fs; wGs[wv] = Gs; }
  __syncthreads();
  float carry = 0.f;
  for (int w = 0; w < wv; ++w) carry = wFs[w] * carry + wGs[w];
  float Fpr = __shfl_up(Fs, 1);
  float Gpr = __shfl_up(Gs, 1);
  float cin = (lane == 0) ? carry : Fpr * carry + Gpr;

  float c = cin;
  float4 r0, r1, r2, r3;
#define QSTEP(fv, gv, ov, e, dst) \
  { c = (float)fv[e] * c + (float)gv[e]; dst = (float)ov[e] * c; }
  QSTEP(f0, g0, o0, 0, r0.x) QSTEP(f0, g0, o0, 1, r0.y)
  QSTEP(f0, g0, o0, 2, r0.z) QSTEP(f0, g0, o0, 3, r0.w)
  QSTEP(f0, g0, o0, 4, r1.x) QSTEP(f0, g0, o0, 5, r1.y)
  QSTEP(f0, g0, o0, 6, r1.z) QSTEP(f0, g0, o0, 7, r1.w)
  QSTEP(f1, g1, o1, 0, r2.x) QSTEP(f1, g1, o1, 1, r2.y)
  QSTEP(f1, g1, o1, 2, r2.z) QSTEP(f1, g1, o1, 3, r2.w)
  QSTEP(f1, g1, o1, 4, r3.x) QSTEP(f1, g1, o1, 5, r3.y)
  QSTEP(f1, g1, o1, 6, r3.z) QSTEP(f1, g1, o1, 7, r3.w)
#undef QSTEP
  {
    int obl = 4 * i;
    int s0 = (obl + 0) ^ (((obl + 0) >> 3) & 7);
    int s1 = (obl + 1) ^ (((obl + 1) >> 3) & 7);
    int s2 = (obl + 2) ^ (((obl + 2) >> 3) & 7);
    int s3 = (obl + 3) ^ (((obl + 3) >> 3) & 7);
    *(float4*)((char*)sOut + s0 * 16) = r0;
    *(float4*)((char*)sOut + s1 * 16) = r1;
    *(float4*)((char*)sOut + s2 * 16) = r2;
    *(float4*)((char*)sOut + s3 * 16) = r3;
  }
  __syncthreads();

  float* og = out + (size_t)blockIdx.x * T_DIM;
#pragma unroll
  for (int it = 0; it < 4; ++it) {
    int idx = it * 256 + tid;
    int sb = idx ^ ((idx >> 3) & 7);
    *(float4*)(og + idx * 4) = *(float4*)((char*)sOut + sb * 16);
  }
}

// ---------------------------------------------------------------------------
extern "C" void kernel_launch(void* const* d_in, const int* in_sizes, int n_in,
                              void* d_out, int out_size, void* d_ws, size_t ws_size,
                              hipStream_t stream) {
  (void)in_sizes; (void)n_in; (void)out_size; (void)ws_size;
  const float* x  = (const float*)d_in[0];
  const float* wz = (const float*)d_in[1];
  const float* bz = (const float*)d_in[2];
  const float* wf = (const float*)d_in[3];
  const float* bf = (const float*)d_in[4];
  const float* wo = (const float*)d_in[5];
  const float* bo = (const float*)d_in[6];
  const float* wi = (const float*)d_in[7];
  const float* bi = (const float*)d_in[8];

  char* ws = (char*)d_ws;
  const size_t MB = 1ull << 20;
  _Float16* A16 = (_Float16*)(ws);                 //   4 MB
  _Float16* XTg = (_Float16*)(ws + 4 * MB);        //  ~32.01 MB  [B][T+1][512]
  _Float16* FGO = (_Float16*)(ws + 40 * MB);       //  96 MB  [B*H][3][T]

  prep<<<4096 + 4096, 256, 0, stream>>>(x, wz, wf, wo, wi, XTg, A16);
  qrnn_gemm<<<B_DIM * 16 * 32, 256, 0, stream>>>(A16, XTg, bz, bf, bo, bi, FGO);
  scan_fused<<<B_DIM * H_DIM, 256, 0, stream>>>(FGO, (float*)d_out);
}